// Round 1
// baseline (262.506 us; speedup 1.0000x reference)
//
#include <hip/hip_runtime.h>
#include <stdint.h>

#define NTOK 4096
#define CDIM 512
#define HEADS 8
#define DHEAD 64
#define LROW 72   // padded LDS row (72 elems = 144 B = 9*16B -> conflict-free-ish)

typedef __bf16 bf16x8 __attribute__((ext_vector_type(8)));
typedef float f32x4 __attribute__((ext_vector_type(4)));

__device__ __forceinline__ unsigned short f2bf(float f) {
    unsigned int u = __builtin_bit_cast(unsigned int, f);
    unsigned int r = (u + 0x7FFFu + ((u >> 16) & 1u)) >> 16;
    return (unsigned short)r;
}

__device__ __forceinline__ f32x4 mfma16(bf16x8 a, bf16x8 b, f32x4 c) {
    return __builtin_amdgcn_mfma_f32_16x16x32_bf16(a, b, c, 0, 0, 0);
}

// ---------------- fp32 -> bf16 cast, 4 elems/thread ----------------
__global__ void cast_bf16_k(const float* __restrict__ in,
                            unsigned short* __restrict__ out, int n) {
    int i = (blockIdx.x * 256 + threadIdx.x) * 4;
    if (i < n) {
        const float4 v = *(const float4*)(in + i);
        ushort4 o;
        o.x = f2bf(v.x); o.y = f2bf(v.y); o.z = f2bf(v.z); o.w = f2bf(v.w);
        *(ushort4*)(out + i) = o;
    }
}

// ---------------- bf16 GEMM, C = A * B^T (+bias), 128x128 tile ----------------
// A: MxK row-major bf16, Bm: NnxK row-major bf16.
// MODE 0: QKV epilogue -> scatter bf16 to q[H][N][D], k[H][N][D], vT[H][D][N], q*=scale
// MODE 1: proj epilogue -> fp32 store to c_out (row-major M x Nn)
template<int MODE>
__global__ __launch_bounds__(256) void gemm_bt(
    const unsigned short* __restrict__ A,
    const unsigned short* __restrict__ Bm,
    const float* __restrict__ bias,
    const float* __restrict__ scale_p,
    unsigned short* __restrict__ qkv_out,
    float* __restrict__ c_out,
    int M, int Nn, int K)
{
    __shared__ __align__(16) unsigned short lA[128 * 32];
    __shared__ __align__(16) unsigned short lB[128 * 32];

    const int tid = threadIdx.x;
    const int mBase = blockIdx.y * 128, nBase = blockIdx.x * 128;
    const int lane = tid & 63, w = tid >> 6;
    const int l16 = lane & 15, quad = lane >> 4;
    const int wr = (w >> 1) * 64, wc = (w & 1) * 64;

    f32x4 acc[4][4] = {};

    for (int kt = 0; kt < K; kt += 32) {
        __syncthreads();
#pragma unroll
        for (int i = 0; i < 2; ++i) {
            const int c = tid + i * 256;       // chunk of 8 bf16
            const int fe = c * 8;
            const int row = fe >> 5, col = fe & 31;
            *(uint4*)&lA[fe] = *(const uint4*)&A[(size_t)(mBase + row) * K + kt + col];
            *(uint4*)&lB[fe] = *(const uint4*)&Bm[(size_t)(nBase + row) * K + kt + col];
        }
        __syncthreads();

        bf16x8 af[4], bfr[4];
#pragma unroll
        for (int i = 0; i < 4; ++i)
            af[i] = *(const bf16x8*)&lA[(wr + i * 16 + l16) * 32 + quad * 8];
#pragma unroll
        for (int j = 0; j < 4; ++j)
            bfr[j] = *(const bf16x8*)&lB[(wc + j * 16 + l16) * 32 + quad * 8];
#pragma unroll
        for (int i = 0; i < 4; ++i)
#pragma unroll
            for (int j = 0; j < 4; ++j)
                acc[i][j] = mfma16(af[i], bfr[j], acc[i][j]);
    }

    const float scl = (MODE == 0) ? scale_p[0] : 0.f;
#pragma unroll
    for (int i = 0; i < 4; ++i)
#pragma unroll
        for (int j = 0; j < 4; ++j)
#pragma unroll
            for (int r = 0; r < 4; ++r) {
                const int grow = mBase + wr + i * 16 + quad * 4 + r;
                const int gcol = nBase + wc + j * 16 + l16;
                float v = acc[i][j][r] + bias[gcol];
                if (MODE == 1) {
                    c_out[(size_t)grow * Nn + gcol] = v;
                } else {
                    const int three = gcol >> 9;        // 0:q 1:k 2:v
                    const int h = (gcol >> 6) & 7;
                    const int dd = gcol & 63;
                    size_t dst;
                    if (three == 0) { v *= scl; dst = ((size_t)h * NTOK + grow) * DHEAD + dd; }
                    else if (three == 1) { dst = (size_t)NTOK * CDIM + ((size_t)h * NTOK + grow) * DHEAD + dd; }
                    else { dst = (size_t)2 * NTOK * CDIM + ((size_t)h * DHEAD + dd) * NTOK + grow; } // V transposed
                    qkv_out[dst] = f2bf(v);
                }
            }
}

// ---------------- flash attention: 1 block = (head, 64 Q rows), 4 waves x 16 rows ----------------
__global__ __launch_bounds__(256) void flash_attn_k(
    const unsigned short* __restrict__ qp,   // [H][N][D] (pre-scaled)
    const unsigned short* __restrict__ kp,   // [H][N][D]
    const unsigned short* __restrict__ vtp,  // [H][D][N]
    unsigned short* __restrict__ attn_out)   // [N][C]
{
    __shared__ __align__(16) unsigned short sQ[64 * LROW];
    __shared__ __align__(16) unsigned short sK[64 * LROW];
    __shared__ __align__(16) unsigned short sVt[64 * LROW];
    __shared__ __align__(16) unsigned short sP[4][16 * LROW];

    const int tid = threadIdx.x;
    const int h = blockIdx.y;
    const int qBase = blockIdx.x * 64;
    const int lane = tid & 63, w = tid >> 6;
    const int l16 = lane & 15, quad = lane >> 4;

    { // load Q tile once (64 rows x 64 cols)
        const size_t base = ((size_t)h * NTOK + qBase) * DHEAD;
#pragma unroll
        for (int i = 0; i < 2; ++i) {
            const int u = tid + i * 256;
            const int r = u >> 3, c8 = (u & 7) * 8;
            *(uint4*)&sQ[r * LROW + c8] = *(const uint4*)&qp[base + (size_t)r * DHEAD + c8];
        }
    }

    f32x4 oacc[4] = {};
    float mrow[4] = {-1e30f, -1e30f, -1e30f, -1e30f};
    float lrow[4] = {0.f, 0.f, 0.f, 0.f};

    for (int kt = 0; kt < NTOK / 64; ++kt) {
        const int kBase = kt * 64;
        __syncthreads();   // previous iter readers done before restage
        {
            const size_t kb = ((size_t)h * NTOK + kBase) * DHEAD;
#pragma unroll
            for (int i = 0; i < 2; ++i) {
                const int u = tid + i * 256;
                const int r = u >> 3, c8 = (u & 7) * 8;
                *(uint4*)&sK[r * LROW + c8] = *(const uint4*)&kp[kb + (size_t)r * DHEAD + c8];
                *(uint4*)&sVt[r * LROW + c8] =
                    *(const uint4*)&vtp[((size_t)h * DHEAD + r) * NTOK + kBase + c8];
            }
        }
        __syncthreads();

        // S = Q K^T : this wave's 16 rows x 64 keys
        f32x4 s[4];
#pragma unroll
        for (int j = 0; j < 4; ++j) {
            f32x4 a = {};
#pragma unroll
            for (int ks = 0; ks < 2; ++ks) {
                bf16x8 aq = *(const bf16x8*)&sQ[(w * 16 + l16) * LROW + ks * 32 + quad * 8];
                bf16x8 bk = *(const bf16x8*)&sK[(j * 16 + l16) * LROW + ks * 32 + quad * 8];
                a = mfma16(aq, bk, a);
            }
            s[j] = a;
        }

        // online softmax (rows quad*4+r live replicated across the quad's 16 lanes)
        float alpha[4];
#pragma unroll
        for (int r = 0; r < 4; ++r) {
            float mx = fmaxf(fmaxf(s[0][r], s[1][r]), fmaxf(s[2][r], s[3][r]));
#pragma unroll
            for (int off = 1; off < 16; off <<= 1) mx = fmaxf(mx, __shfl_xor(mx, off, 64));
            const float mnew = fmaxf(mrow[r], mx);
            alpha[r] = __expf(mrow[r] - mnew);
            mrow[r] = mnew;
            float ps = 0.f;
#pragma unroll
            for (int j = 0; j < 4; ++j) { s[j][r] = __expf(s[j][r] - mnew); ps += s[j][r]; }
#pragma unroll
            for (int off = 1; off < 16; off <<= 1) ps += __shfl_xor(ps, off, 64);
            lrow[r] = lrow[r] * alpha[r] + ps;
        }
#pragma unroll
        for (int jd = 0; jd < 4; ++jd)
#pragma unroll
            for (int r = 0; r < 4; ++r) oacc[jd][r] *= alpha[r];

        // P (C-layout) -> LDS -> A-layout
#pragma unroll
        for (int j = 0; j < 4; ++j)
#pragma unroll
            for (int r = 0; r < 4; ++r)
                sP[w][(quad * 4 + r) * LROW + j * 16 + l16] = f2bf(s[j][r]);
        __syncthreads();

        // O += P * V   (B operand = V^T from sVt, contiguous)
#pragma unroll
        for (int ks = 0; ks < 2; ++ks) {
            bf16x8 ap = *(const bf16x8*)&sP[w][l16 * LROW + ks * 32 + quad * 8];
#pragma unroll
            for (int jd = 0; jd < 4; ++jd) {
                bf16x8 bv = *(const bf16x8*)&sVt[(jd * 16 + l16) * LROW + ks * 32 + quad * 8];
                oacc[jd] = mfma16(ap, bv, oacc[jd]);
            }
        }
    }

    float invl[4];
#pragma unroll
    for (int r = 0; r < 4; ++r) invl[r] = 1.f / lrow[r];
#pragma unroll
    for (int jd = 0; jd < 4; ++jd)
#pragma unroll
        for (int r = 0; r < 4; ++r) {
            const int row = qBase + w * 16 + quad * 4 + r;
            const int col = h * DHEAD + jd * 16 + l16;
            attn_out[(size_t)row * CDIM + col] = f2bf(oacc[jd][r] * invl[r]);
        }
}

extern "C" void kernel_launch(void* const* d_in, const int* in_sizes, int n_in,
                              void* d_out, int out_size, void* d_ws, size_t ws_size,
                              hipStream_t stream) {
    const float* x       = (const float*)d_in[0];
    // d_in[1] = num_heads (unused, static 8), d_in[2] = bias (unused)
    const float* scale_p = (const float*)d_in[3];
    const float* Wqkv    = (const float*)d_in[4];
    const float* bqkv    = (const float*)d_in[5];
    const float* Wproj   = (const float*)d_in[6];
    const float* bproj   = (const float*)d_in[7];
    float* out = (float*)d_out;

    // workspace layout (bytes)
    char* ws = (char*)d_ws;
    const size_t OFF_XB    = 0;                       // 4096*512 bf16   = 4 MB
    const size_t OFF_WQKV  = OFF_XB + 4194304;        // 1536*512 bf16   = 1.5 MB
    const size_t OFF_WPROJ = OFF_WQKV + 1572864;      // 512*512 bf16    = 0.5 MB
    const size_t OFF_QKV   = OFF_WPROJ + 524288;      // 3*4096*512 bf16 = 12 MB
    const size_t OFF_ATTN  = OFF_QKV + 12582912;      // 4096*512 bf16   = 4 MB
    const size_t NEEDED    = OFF_ATTN + 4194304;
    if (ws_size < NEEDED) return;  // avoid corrupting memory if ws too small

    unsigned short* xb     = (unsigned short*)(ws + OFF_XB);
    unsigned short* wqkvb  = (unsigned short*)(ws + OFF_WQKV);
    unsigned short* wprojb = (unsigned short*)(ws + OFF_WPROJ);
    unsigned short* qkvb   = (unsigned short*)(ws + OFF_QKV);
    unsigned short* attnb  = (unsigned short*)(ws + OFF_ATTN);

    cast_bf16_k<<<2048, 256, 0, stream>>>(x,     xb,     NTOK * CDIM);
    cast_bf16_k<<<768,  256, 0, stream>>>(Wqkv,  wqkvb,  3 * CDIM * CDIM);
    cast_bf16_k<<<256,  256, 0, stream>>>(Wproj, wprojb, CDIM * CDIM);

    gemm_bt<0><<<dim3(12, 32), 256, 0, stream>>>(xb, wqkvb, bqkv, scale_p,
                                                 qkvb, nullptr, NTOK, 3 * CDIM, CDIM);

    const unsigned short* qb  = qkvb;
    const unsigned short* kb  = qkvb + (size_t)NTOK * CDIM;
    const unsigned short* vtb = qkvb + (size_t)2 * NTOK * CDIM;
    flash_attn_k<<<dim3(64, 8), 256, 0, stream>>>(qb, kb, vtb, attnb);

    gemm_bt<1><<<dim3(4, 32), 256, 0, stream>>>(attnb, wprojb, bproj, nullptr,
                                                nullptr, out, NTOK, CDIM, CDIM);
}

// Round 2
// 181.203 us; speedup vs baseline: 1.4487x; 1.4487x over previous
//
#include <hip/hip_runtime.h>
#include <stdint.h>

#define NTOK 4096
#define CDIM 512
#define HEADS 8
#define DHEAD 64
#define PHEAD (NTOK * DHEAD)          // 262144 elems per head per tensor

typedef __bf16 bf16x8 __attribute__((ext_vector_type(8)));
typedef short short4v __attribute__((ext_vector_type(4)));
typedef float f32x4 __attribute__((ext_vector_type(4)));

__device__ __forceinline__ unsigned short f2bf(float f) {
    unsigned int u = __builtin_bit_cast(unsigned int, f);
    unsigned int r = (u + 0x7FFFu + ((u >> 16) & 1u)) >> 16;
    return (unsigned short)r;
}

__device__ __forceinline__ f32x4 mfma32(bf16x8 a, bf16x8 b, f32x4 c) {
    return __builtin_amdgcn_mfma_f32_16x16x32_bf16(a, b, c, 0, 0, 0);
}
__device__ __forceinline__ f32x4 mfma16(short4v a, short4v b, f32x4 c) {
    return __builtin_amdgcn_mfma_f32_16x16x16bf16_1k(a, b, c, 0, 0, 0);
}

// ---------------- fused fp32 -> bf16 casts (x, Wqkv, Wproj in one grid) ----------------
__global__ void cast3_k(const float* __restrict__ x, const float* __restrict__ wq,
                        const float* __restrict__ wp,
                        unsigned short* __restrict__ xb, unsigned short* __restrict__ wqb,
                        unsigned short* __restrict__ wpb) {
    const int b = blockIdx.x;
    const float* src; unsigned short* dst; int base;
    if (b < 2048)      { src = x;  dst = xb;  base = b * 1024; }
    else if (b < 2816) { src = wq; dst = wqb; base = (b - 2048) * 1024; }
    else               { src = wp; dst = wpb; base = (b - 2816) * 1024; }
    const int i = base + threadIdx.x * 4;
    const float4 v = *(const float4*)(src + i);
    ushort4 o;
    o.x = f2bf(v.x); o.y = f2bf(v.y); o.z = f2bf(v.z); o.w = f2bf(v.w);
    *(ushort4*)(dst + i) = o;
}

// ---------------- bf16 GEMM, C = A * B^T (+bias), 128x128 tile ----------------
// MODE 0: QKV epilogue -> scatter bf16 into pre-fragmented q/k/v layouts, q *= scale*log2e
// MODE 1: proj epilogue -> fp32 store to c_out (row-major M x Nn)
template<int MODE>
__global__ __launch_bounds__(256) void gemm_bt(
    const unsigned short* __restrict__ A,
    const unsigned short* __restrict__ Bm,
    const float* __restrict__ bias,
    const float* __restrict__ scale_p,
    unsigned short* __restrict__ qkv_out,
    float* __restrict__ c_out,
    int M, int Nn, int K)
{
    __shared__ __align__(16) unsigned short lA[128 * 32];
    __shared__ __align__(16) unsigned short lB[128 * 32];

    const int tid = threadIdx.x;
    const int mBase = blockIdx.y * 128, nBase = blockIdx.x * 128;
    const int lane = tid & 63, w = tid >> 6;
    const int l16 = lane & 15, quad = lane >> 4;
    const int wr = (w >> 1) * 64, wc = (w & 1) * 64;

    f32x4 acc[4][4] = {};

    for (int kt = 0; kt < K; kt += 32) {
        __syncthreads();
#pragma unroll
        for (int i = 0; i < 2; ++i) {
            const int c = tid + i * 256;
            const int fe = c * 8;
            const int row = fe >> 5, col = fe & 31;
            *(uint4*)&lA[fe] = *(const uint4*)&A[(size_t)(mBase + row) * K + kt + col];
            *(uint4*)&lB[fe] = *(const uint4*)&Bm[(size_t)(nBase + row) * K + kt + col];
        }
        __syncthreads();

        bf16x8 af[4], bfr[4];
#pragma unroll
        for (int i = 0; i < 4; ++i)
            af[i] = *(const bf16x8*)&lA[(wr + i * 16 + l16) * 32 + quad * 8];
#pragma unroll
        for (int j = 0; j < 4; ++j)
            bfr[j] = *(const bf16x8*)&lB[(wc + j * 16 + l16) * 32 + quad * 8];
#pragma unroll
        for (int i = 0; i < 4; ++i)
#pragma unroll
            for (int j = 0; j < 4; ++j)
                acc[i][j] = mfma32(af[i], bfr[j], acc[i][j]);
    }

    const float scl = (MODE == 0) ? scale_p[0] * 1.44269504f : 0.f;  // fold log2(e)
#pragma unroll
    for (int i = 0; i < 4; ++i)
#pragma unroll
        for (int j = 0; j < 4; ++j)
#pragma unroll
            for (int r = 0; r < 4; ++r) {
                const int grow = mBase + wr + i * 16 + quad * 4 + r;
                const int gcol = nBase + wc + j * 16 + l16;
                float v = acc[i][j][r] + bias[gcol];
                if (MODE == 1) {
                    c_out[(size_t)grow * Nn + gcol] = v;
                } else {
                    const int three = gcol >> 9;        // 0:q 1:k 2:v
                    const int h = (gcol >> 6) & 7;
                    const int dd = gcol & 63;
                    size_t dst;
                    if (three < 2) {
                        if (three == 0) v *= scl;
                        // frag layout: [h][t16][ks][quad*16+l16][8]
                        dst = (size_t)three * PHEAD * HEADS +
                              ((((size_t)h * 256 + (grow >> 4)) * 2 + (dd >> 5)) * 64 +
                               ((dd >> 3) & 3) * 16 + (grow & 15)) * 8 + (dd & 7);
                    } else {
                        // V^T frag layout: [h][k16][dt][quad*16+l16][4]
                        dst = (size_t)2 * PHEAD * HEADS +
                              ((((size_t)h * 256 + (grow >> 4)) * 4 + (dd >> 4)) * 64 +
                               ((grow >> 2) & 3) * 16 + (dd & 15)) * 4 + (grow & 3);
                    }
                    qkv_out[dst] = f2bf(v);
                }
            }
}

// ---------------- flash attention v2: LDS-free, barrier-free main loop ----------------
// Block = 32 Q rows x 1 head, 4 waves each own 1/4 of the keys (interleaved 64-key tiles).
// S^T = K Q^T via 16x16x32 (A=K-frag, B=Q-frag) -> per-lane q, in-register softmax.
// O^T = V^T P^T via 16x16x16 (A=V^T-frag, B=exp'd S^T already in B-frag layout).
// End: 4-way flash merge via LDS.
__global__ __launch_bounds__(256) void flash2_k(
    const unsigned short* __restrict__ qf,
    const unsigned short* __restrict__ kf,
    const unsigned short* __restrict__ vf,
    unsigned short* __restrict__ attn_out)   // [N][C] bf16
{
    __shared__ float ldsO[4][32][68];   // [wave][q][d] (+4 pad vs 64 to break conflicts)
    __shared__ float sml[2][4][32];     // [m|l][wave][q]

    const int tid = threadIdx.x;
    const int w = tid >> 6, lane = tid & 63;
    const int l16 = lane & 15, quad = lane >> 4;
    const int h = blockIdx.y, qb = blockIdx.x;

    const unsigned short* qh = qf + (size_t)h * PHEAD;
    const unsigned short* kh = kf + (size_t)h * PHEAD;
    const unsigned short* vh = vf + (size_t)h * PHEAD;

    bf16x8 qfr[2][2];
#pragma unroll
    for (int qt = 0; qt < 2; ++qt)
#pragma unroll
        for (int ks = 0; ks < 2; ++ks)
            qfr[qt][ks] = *(const bf16x8*)&qh[(((size_t)(qb * 2 + qt) * 2 + ks) * 64 + lane) * 8];

    f32x4 oacc[4][2] = {};              // [dtile][qtile], O^T: d=quad*4+r, q=l16
    float m[2] = {-3.0e38f, -3.0e38f};
    float l[2] = {0.f, 0.f};

    for (int it = 0; it < 16; ++it) {
        const int kt64 = it * 4 + w;    // this wave's 64-key tile
        f32x4 s[4][2];
#pragma unroll
        for (int kt = 0; kt < 4; ++kt) {
            const int k16 = kt64 * 4 + kt;
            const bf16x8 k0 = *(const bf16x8*)&kh[(((size_t)k16 * 2 + 0) * 64 + lane) * 8];
            const bf16x8 k1 = *(const bf16x8*)&kh[(((size_t)k16 * 2 + 1) * 64 + lane) * 8];
#pragma unroll
            for (int qt = 0; qt < 2; ++qt) {
                f32x4 a = {};
                a = mfma32(k0, qfr[qt][0], a);
                a = mfma32(k1, qfr[qt][1], a);
                s[kt][qt] = a;
            }
        }

        short4v pf[4][2];
        float alpha[2];
#pragma unroll
        for (int qt = 0; qt < 2; ++qt) {
            float mx = s[0][qt][0];
#pragma unroll
            for (int kt = 0; kt < 4; ++kt)
#pragma unroll
                for (int r = 0; r < 4; ++r) mx = fmaxf(mx, s[kt][qt][r]);
            mx = fmaxf(mx, __shfl_xor(mx, 16, 64));
            mx = fmaxf(mx, __shfl_xor(mx, 32, 64));
            const float mn = fmaxf(m[qt], mx);
            alpha[qt] = __builtin_amdgcn_exp2f(m[qt] - mn);
            m[qt] = mn;
            float ps = 0.f;
#pragma unroll
            for (int kt = 0; kt < 4; ++kt) {
                short4v p4;
#pragma unroll
                for (int r = 0; r < 4; ++r) {
                    const float p = __builtin_amdgcn_exp2f(s[kt][qt][r] - mn);
                    ps += p;
                    p4[r] = (short)f2bf(p);
                }
                pf[kt][qt] = p4;
            }
            ps += __shfl_xor(ps, 16, 64);
            ps += __shfl_xor(ps, 32, 64);
            l[qt] = l[qt] * alpha[qt] + ps;
#pragma unroll
            for (int dt = 0; dt < 4; ++dt) oacc[dt][qt] *= alpha[qt];
        }

#pragma unroll
        for (int kt = 0; kt < 4; ++kt) {
            const int k16 = kt64 * 4 + kt;
#pragma unroll
            for (int dt = 0; dt < 4; ++dt) {
                const short4v vfr = *(const short4v*)&vh[(((size_t)k16 * 4 + dt) * 64 + lane) * 4];
#pragma unroll
                for (int qt = 0; qt < 2; ++qt)
                    oacc[dt][qt] = mfma16(vfr, pf[kt][qt], oacc[dt][qt]);
            }
        }
    }

    // ---- 4-way wave merge ----
    if (quad == 0) {
#pragma unroll
        for (int qt = 0; qt < 2; ++qt) {
            sml[0][w][qt * 16 + l16] = m[qt];
            sml[1][w][qt * 16 + l16] = l[qt];
        }
    }
    __syncthreads();
#pragma unroll
    for (int qt = 0; qt < 2; ++qt) {
        const int q = qt * 16 + l16;
        const float M = fmaxf(fmaxf(sml[0][0][q], sml[0][1][q]),
                              fmaxf(sml[0][2][q], sml[0][3][q]));
        const float wt = __builtin_amdgcn_exp2f(m[qt] - M);
#pragma unroll
        for (int dt = 0; dt < 4; ++dt) {
            const f32x4 v = oacc[dt][qt] * wt;
            *(f32x4*)&ldsO[w][q][dt * 16 + quad * 4] = v;
        }
    }
    __syncthreads();
    {
        const int q = tid >> 3, dz = (tid & 7) * 8;
        const float M = fmaxf(fmaxf(sml[0][0][q], sml[0][1][q]),
                              fmaxf(sml[0][2][q], sml[0][3][q]));
        float L = 0.f;
#pragma unroll
        for (int ww = 0; ww < 4; ++ww)
            L += sml[1][ww][q] * __builtin_amdgcn_exp2f(sml[0][ww][q] - M);
        const float inv = 1.f / L;
        unsigned short o8[8];
#pragma unroll
        for (int i = 0; i < 8; ++i) {
            const float v = ldsO[0][q][dz + i] + ldsO[1][q][dz + i] +
                            ldsO[2][q][dz + i] + ldsO[3][q][dz + i];
            o8[i] = f2bf(v * inv);
        }
        *(uint4*)&attn_out[(size_t)(qb * 32 + q) * CDIM + h * DHEAD + dz] = *(uint4*)o8;
    }
}

extern "C" void kernel_launch(void* const* d_in, const int* in_sizes, int n_in,
                              void* d_out, int out_size, void* d_ws, size_t ws_size,
                              hipStream_t stream) {
    const float* x       = (const float*)d_in[0];
    const float* scale_p = (const float*)d_in[3];
    const float* Wqkv    = (const float*)d_in[4];
    const float* bqkv    = (const float*)d_in[5];
    const float* Wproj   = (const float*)d_in[6];
    const float* bproj   = (const float*)d_in[7];
    float* out = (float*)d_out;

    char* ws = (char*)d_ws;
    const size_t OFF_XB    = 0;                       // 4096*512 bf16   = 4 MB
    const size_t OFF_WQKV  = OFF_XB + 4194304;        // 1536*512 bf16   = 1.5 MB
    const size_t OFF_WPROJ = OFF_WQKV + 1572864;      // 512*512 bf16    = 0.5 MB
    const size_t OFF_QKV   = OFF_WPROJ + 524288;      // 3*4096*512 bf16 = 12 MB
    const size_t OFF_ATTN  = OFF_QKV + 12582912;      // 4096*512 bf16   = 4 MB
    const size_t NEEDED    = OFF_ATTN + 4194304;
    if (ws_size < NEEDED) return;

    unsigned short* xb     = (unsigned short*)(ws + OFF_XB);
    unsigned short* wqkvb  = (unsigned short*)(ws + OFF_WQKV);
    unsigned short* wprojb = (unsigned short*)(ws + OFF_WPROJ);
    unsigned short* qkvb   = (unsigned short*)(ws + OFF_QKV);
    unsigned short* attnb  = (unsigned short*)(ws + OFF_ATTN);

    cast3_k<<<3072, 256, 0, stream>>>(x, Wqkv, Wproj, xb, wqkvb, wprojb);

    gemm_bt<0><<<dim3(12, 32), 256, 0, stream>>>(xb, wqkvb, bqkv, scale_p,
                                                 qkvb, nullptr, NTOK, 3 * CDIM, CDIM);

    const unsigned short* qfr = qkvb;
    const unsigned short* kfr = qkvb + (size_t)PHEAD * HEADS;
    const unsigned short* vfr = qkvb + (size_t)2 * PHEAD * HEADS;
    flash2_k<<<dim3(128, 8), 256, 0, stream>>>(qfr, kfr, vfr, attnb);

    gemm_bt<1><<<dim3(4, 32), 256, 0, stream>>>(attnb, wprojb, bproj, nullptr,
                                                nullptr, out, NTOK, CDIM, CDIM);
}